// Round 7
// baseline (460.511 us; speedup 1.0000x reference)
//
#include <hip/hip_runtime.h>
#include <hip/hip_fp16.h>
#include <stdint.h>

typedef unsigned int   uint32;
typedef unsigned short ushort_t;
typedef _Float16 half8    __attribute__((ext_vector_type(8)));
typedef float    floatx4  __attribute__((ext_vector_type(4)));
typedef float    floatx16 __attribute__((ext_vector_type(16)));

#define DEVINL __device__ __forceinline__

#define N_FRAGS 1184            // total 1KB weight fragments (32x32x16 layout)

// ---------------------------------------------------------------------------
// 32x32x16 f16 MFMA everywhere. Why vs 16x16x32: ~19% fewer matrix-pipe
// cycles per FLOP (8.07 cy/32K vs 4.85 cy/16K, m119) and HALF the MFMA
// instruction count -- r0/r4 counters show MfmaUtil 54 + VALUBusy 43 ~= 97%
// combined: the SIMD issue port is the saturated resource, so fewer issued
// instructions is the lever.
//
// Spill fix (r5: 277MB, r6: 167MB scratch): those versions' first MFMA per
// layer was acc = mfma(a,b,vz) -- D != C forces a separate aligned 16-reg
// C-tuple plus result copies (transient spike > cap regardless of 128/168).
// Now acc is explicitly zero-initialized and EVERY MFMA is in-place D==C.
//
// Occupancy: (256,3) -- 3 blocks/CU inter-block overlap is this kernel's
// latency hiding (r2: 1 block/CU -> 35% MfmaUtil; r1/r5: 4 blk/CU spills).
//
// Operand lane maps (r5/r6-verified end-to-end, absmax unchanged):
//   A (weights): lane l holds W[k = kt*16 + (l>>5)*8 + e][n = nt*32 + (l&31)]
//   B (acts):    lane l holds h[m = rt*32 + (l&31)][k = kt*16 + (l>>5)*8 + e]
//   D:           lane l, reg r = D[n = (r&3)+8*(r>>2)+4*(l>>5)][m = l&31]
//
// Fragment-major LDS layout (conflict-free stride-1 b128 B-reads, r4):
//   off(row,f) = (f>>4)*1024 + (row>>5)*512 + (((f>>3)&1)*32 + (row&31))*8 + (f&7)
// ---------------------------------------------------------------------------
DEVINL int fragoff(int row, int f) {
    return (f >> 4)*1024 + (row >> 5)*512
         + ((((f >> 3) & 1) << 5) + (row & 31))*8 + (f & 7);
}

// Packed f16 weight fragments in module-owned device memory. Rewritten every
// launch from restored fp32 inputs -> graph-capture safe. L2-resident.
__device__ __align__(16) ushort_t g_ws[(size_t)N_FRAGS * 512];

DEVINL ushort_t f2h_u(float v) { return __half_as_ushort(__float2half(v)); }

// ---------------------------------------------------------------------------
// A-fragment pack: lane (s=l>>5, c=l&31) holds W[k=kt*16+s*8+j][n=nt*32+c].
// skip63 (layer-4 concat): k<63 -> row k, k==63 -> 0, k>63 -> row k-1.
// ---------------------------------------------------------------------------
DEVINL uint4 make_frag_qword(const float* __restrict__ W, int Kr, int Nr,
                             int skip63, int kt, int nt, int s, int c)
{
    const int n = nt*32 + c;
    uint32 pk[4];
    #pragma unroll
    for (int jj = 0; jj < 4; ++jj) {
        ushort_t h2[2];
        #pragma unroll
        for (int e = 0; e < 2; ++e) {
            const int k = kt*16 + s*8 + jj*2 + e;
            float v = 0.f;
            if (n < Nr) {
                if (skip63) {
                    if (k != 63) { const int rr = (k < 63) ? k : (k - 1); v = W[(size_t)rr*Nr + n]; }
                } else if (k < Kr) {
                    v = W[(size_t)k*Nr + n];
                }
            }
            h2[e] = f2h_u(v);
        }
        pk[jj] = (uint32)h2[0] | ((uint32)h2[1] << 16);
    }
    return make_uint4(pk[0], pk[1], pk[2], pk[3]);
}

// frag layout per layer: index = kt*NT + nt (kt-major). Per-layer frag counts:
// L0 4x8=32, L1-7/fin 16x8=128 (L4 20x8=160), sigma 16x1, rgb1 18x4=72,
// rgb2 8x1. foff cumulative below.
__global__ __launch_bounds__(256) void prep_weights(
    const float* __restrict__ w0, const float* __restrict__ w1,
    const float* __restrict__ w2, const float* __restrict__ w3,
    const float* __restrict__ w4, const float* __restrict__ w5,
    const float* __restrict__ w6, const float* __restrict__ w7,
    const float* __restrict__ wf, const float* __restrict__ wsig,
    const float* __restrict__ wr1, const float* __restrict__ wr2)
{
    int gid  = blockIdx.x * 256 + threadIdx.x;
    int frag = gid >> 6;
    if (frag >= N_FRAGS) return;
    int lane = gid & 63;

    constexpr int foff[13] = {0,32,160,288,416,576,704,832,960,1088,1104,1176,1184};
    int t = 0;
    #pragma unroll
    for (int i = 1; i <= 11; ++i) if (frag >= foff[i]) t = i;

    const float* W; int fo, ntc, Kr, Nr;
    switch (t) {
        case 0:  W = w0;   fo = 0;    ntc = 8; Kr = 63;  Nr = 256; break;
        case 1:  W = w1;   fo = 32;   ntc = 8; Kr = 256; Nr = 256; break;
        case 2:  W = w2;   fo = 160;  ntc = 8; Kr = 256; Nr = 256; break;
        case 3:  W = w3;   fo = 288;  ntc = 8; Kr = 256; Nr = 256; break;
        case 4:  W = w4;   fo = 416;  ntc = 8; Kr = 319; Nr = 256; break;
        case 5:  W = w5;   fo = 576;  ntc = 8; Kr = 256; Nr = 256; break;
        case 6:  W = w6;   fo = 704;  ntc = 8; Kr = 256; Nr = 256; break;
        case 7:  W = w7;   fo = 832;  ntc = 8; Kr = 256; Nr = 256; break;
        case 8:  W = wf;   fo = 960;  ntc = 8; Kr = 256; Nr = 256; break;
        case 9:  W = wsig; fo = 1088; ntc = 1; Kr = 256; Nr = 1;   break;
        case 10: W = wr1;  fo = 1104; ntc = 4; Kr = 283; Nr = 128; break;
        default: W = wr2;  fo = 1176; ntc = 1; Kr = 128; Nr = 3;   break;
    }
    int fl = frag - fo;
    int nt = fl % ntc;
    int kt = fl / ntc;
    uint4 pk = make_frag_qword(W, Kr, Nr, (t == 4) ? 1 : 0, kt, nt,
                               lane >> 5, lane & 31);
    *(uint4*)(g_ws + (size_t)frag*512 + lane*8) = pk;
}

// ---------------------------------------------------------------------------
// Layer: D[n][m] = sum_k W[k][n] * h[m][k], 32x32x16 tiles. Wave computes
// 64 rows (rt 0..1) x NT_W*32 feats. A-frags from L2-hot g_ws, B-frags from
// fragment-major LDS (stride-1 b128); depth-1 pipelined. acc explicitly
// zeroed, then every MFMA is in-place (D==C) -- the r5/r6 spill fix. Bias
// is added in the epilogue.
// ---------------------------------------------------------------------------
template <int NT_W, int KT, int KT_SPLIT, int NTT>
DEVINL void run_layer(const ushort_t* __restrict__ wsrc,
                      const ushort_t* __restrict__ in0,
                      const ushort_t* __restrict__ in1,
                      int lane, int nt_lo, floatx16 (&acc)[2][NT_W])
{
    half8 bfr[2][2];
    half8 afr[2][NT_W];

    auto loadk = [&](int kt, int buf) {
        const ushort_t* bb = ((kt < KT_SPLIT) ? in0 + kt*1024
                                              : in1 + (kt - KT_SPLIT)*1024) + lane*8;
        #pragma unroll
        for (int rt = 0; rt < 2; ++rt)
            bfr[buf][rt] = *(const half8*)(bb + rt*512);
        const ushort_t* wb = wsrc + (size_t)(kt*NTT + nt_lo)*512 + lane*8;
        #pragma unroll
        for (int nt = 0; nt < NT_W; ++nt)
            afr[buf][nt] = *(const half8*)(wb + nt*512);
    };

    // in-place zero init (accvgpr writes), cheap vs the D!=C tuple copies
    #pragma unroll
    for (int rt = 0; rt < 2; ++rt)
        #pragma unroll
        for (int nt = 0; nt < NT_W; ++nt)
            #pragma unroll
            for (int e = 0; e < 16; ++e)
                acc[rt][nt][e] = 0.f;

    loadk(0, 0);
    #pragma unroll
    for (int kt = 0; kt < KT; ++kt) {
        const int cur = kt & 1;
        if (kt + 1 < KT) loadk(kt + 1, cur ^ 1);
        #pragma unroll
        for (int nt = 0; nt < NT_W; ++nt)
            #pragma unroll
            for (int rt = 0; rt < 2; ++rt)
                acc[rt][nt] = __builtin_amdgcn_mfma_f32_32x32x16_f16(
                    afr[cur][nt], bfr[cur][rt], acc[rt][nt], 0, 0, 0);
    }
}

// epilogue: bias add (+optional relu), pack to f16, store into frag-major LDS.
// Lane l reg r holds D[n = n0+(r&3)+8*(r>>2)+4*s][m = rt*32+c], s=l>>5, c=l&31.
// bias quads: q[p][j] = b[n0+8p+4s+j] -> v(r) += q[r>>2][r&3].
// Store as b64 per r4-group:
//   dst = ((n0>>4)+(r4>>3))*1024 + rt*512 + (((r4>>2)&1)*32 + c)*8 + 4*s
template <int NT_W, bool RELU>
DEVINL void epilogue32(floatx16 (&acc)[2][NT_W], int nt_lo,
                       ushort_t* __restrict__ dsth, const float* __restrict__ bias,
                       int lane)
{
    const int s = lane >> 5, c = lane & 31;
    #pragma unroll
    for (int nt = 0; nt < NT_W; ++nt) {
        const int n0 = (nt_lo + nt)*32;
        floatx4 q[4];
        #pragma unroll
        for (int p = 0; p < 4; ++p)
            q[p] = *(const floatx4*)(bias + n0 + 8*p + 4*s);
        #pragma unroll
        for (int rt = 0; rt < 2; ++rt) {
            #pragma unroll
            for (int r4 = 0; r4 < 16; r4 += 4) {
                float v0 = acc[rt][nt][r4+0] + q[r4>>2][0];
                float v1 = acc[rt][nt][r4+1] + q[r4>>2][1];
                float v2 = acc[rt][nt][r4+2] + q[r4>>2][2];
                float v3 = acc[rt][nt][r4+3] + q[r4>>2][3];
                if (RELU) {
                    v0 = fmaxf(v0, 0.f); v1 = fmaxf(v1, 0.f);
                    v2 = fmaxf(v2, 0.f); v3 = fmaxf(v3, 0.f);
                }
                uint2 u;
                u.x = __builtin_bit_cast(uint32, __builtin_amdgcn_cvt_pkrtz(v0, v1));
                u.y = __builtin_bit_cast(uint32, __builtin_amdgcn_cvt_pkrtz(v2, v3));
                const int dst = ((nt_lo + nt)*2 + (r4 >> 3))*1024 + rt*512
                              + ((((r4 >> 2) & 1) << 5) + c)*8 + 4*s;
                *(uint2*)(dsth + dst) = u;
            }
        }
    }
}

// (256,3): 168-reg cap; steady demand ~150 and (now) no D!=C transients.
// LDS 40KB -> occupancy stays reg-limited at 3 blocks/CU.
__global__ __launch_bounds__(256, 3) void nerf_fused(
    const float* __restrict__ x,
    const float* __restrict__ b0, const float* __restrict__ b1,
    const float* __restrict__ b2, const float* __restrict__ b3,
    const float* __restrict__ b4, const float* __restrict__ b5,
    const float* __restrict__ b6, const float* __restrict__ b7,
    const float* __restrict__ bf, const float* __restrict__ bsig,
    const float* __restrict__ br1, const float* __restrict__ br2,
    float* __restrict__ out)
{
    __shared__ __align__(16) ushort_t shh[16*1024];  // h acts, frag-major, 32KB
    __shared__ __align__(16) ushort_t shx[4*1024];   // xyz posenc 8KB; kb0-1
                                                     // reused for dir after L4
    ushort_t* shd = shx;                             // dir overlay (4KB)

    const int tid  = threadIdx.x;
    const int wave = tid >> 6, lane = tid & 63;
    const int r0 = blockIdx.x * 64;
    const ushort_t* ws = g_ws;
    const int nt_lo2 = wave * 2;

    // ---- xyz positional encoding only (row = lane, job-set = wave) ----
    {
        const int r = lane;
        const float* xr = x + (size_t)(r0 + r)*6;
        for (int j = wave; j < 30; j += 4) {      // xyz: F=10, 3 + f*6 + s*3 + a
            int f = j/3, a = j%3;
            float v = xr[a] * (float)(1 << f);
            shx[fragoff(r, 3 + f*6 + a)]     = f2h_u(sinf(v));
            shx[fragoff(r, 3 + f*6 + 3 + a)] = f2h_u(cosf(v));
        }
        if (wave == 0) {
            #pragma unroll
            for (int a = 0; a < 3; ++a) shx[fragoff(r, a)] = f2h_u(xr[a]);
            shx[fragoff(r, 63)] = 0;              // k-pad must be 0
        }
    }
    __syncthreads();

    const float* BS[8] = {b0,b1,b2,b3,b4,b5,b6,b7};
    const int WO[8] = {0,16384,81920,147456,212992,294912,360448,425984};

    floatx16 acc[2][2];

    // layer 0: 64(xyz) -> 256
    run_layer<2,4,4,8>(ws + WO[0], shx, shx, lane, nt_lo2, acc);
    __syncthreads();
    epilogue32<2,true>(acc, nt_lo2, shh, b0, lane);
    __syncthreads();

    // layers 1..7 (layer 4 = skip-concat: 4 kt from xyz, 16 kt from h)
    #pragma unroll
    for (int l = 1; l < 8; ++l) {
        if (l == 4)
            run_layer<2,20,4,8>(ws + WO[4], shx, shh, lane, nt_lo2, acc);
        else
            run_layer<2,16,16,8>(ws + WO[l], shh, shh, lane, nt_lo2, acc);
        __syncthreads();   // all waves done reading before overwrites
        if (l == 4) {
            // shx now dead: compute dir posenc into its first kb (saves 4KB
            // LDS). Visibility covered by the next barrier.
            const int r = lane;
            const float* xr = x + (size_t)(r0 + r)*6;
            for (int j = wave; j < 12; j += 4) {  // dir: F=4
                int f = j/3, a = j%3;
                float v = xr[3+a] * (float)(1 << f);
                shd[fragoff(r, 3 + f*6 + a)]     = f2h_u(sinf(v));
                shd[fragoff(r, 3 + f*6 + 3 + a)] = f2h_u(cosf(v));
            }
            if (wave == 0) {
                #pragma unroll
                for (int a = 0; a < 3; ++a) shd[fragoff(r, a)] = f2h_u(xr[3+a]);
                #pragma unroll
                for (int kq = 27; kq < 32; ++kq) shd[fragoff(r, kq)] = 0;
            }
        }
        epilogue32<2,true>(acc, nt_lo2, shh, BS[l], lane);
        __syncthreads();
    }

    // sigma head: wave 0 only (barrier-free region, overlaps others' final).
    // Output feature 0 = reg 0, lanes 0..31 (n = (r&3)+8*(r>>2)+4*s == 0).
    if (wave == 0) {
        floatx16 sacc[2][1];
        run_layer<1,16,16,1>(ws + 557056, shh, shh, lane, 0, sacc);
        if (lane < 32) {
            const float bs_ = bsig[0];
            #pragma unroll
            for (int rt = 0; rt < 2; ++rt)
                out[(size_t)(r0 + rt*32 + lane)*4 + 3] = sacc[rt][0][0] + bs_;
        }
    }

    // final: 256 -> 256, NO relu (barrier also covers in-flight sigma reads)
    run_layer<2,16,16,8>(ws + 491520, shh, shh, lane, nt_lo2, acc);
    __syncthreads();
    epilogue32<2,false>(acc, nt_lo2, shh, bf, lane);
    __syncthreads();

    // rgb1: [final(256) | dir(27->32)] -> 128, relu. NT=4, wave w owns nt=w.
    {
        floatx16 racc[2][1];
        run_layer<1,18,16,4>(ws + 565248, shh, shd, lane, wave, racc);
        __syncthreads();
        epilogue32<1,true>(racc, wave, shh, br1, lane);
        __syncthreads();
    }

    // rgb2: 128 -> 3, sigmoid, store rgb (wave 0 only). Channels = regs 0..2,
    // lanes 0..31.
    if (wave == 0) {
        floatx16 cacc[2][1];
        run_layer<1,8,8,1>(ws + 602112, shh, shh, lane, 0, cacc);
        if (lane < 32) {
            const float c0 = br2[0], c1 = br2[1], c2 = br2[2];
            #pragma unroll
            for (int rt = 0; rt < 2; ++rt) {
                const size_t o = (size_t)(r0 + rt*32 + lane)*4;
                out[o+0] = 1.f/(1.f + expf(-(cacc[rt][0][0] + c0)));
                out[o+1] = 1.f/(1.f + expf(-(cacc[rt][0][1] + c1)));
                out[o+2] = 1.f/(1.f + expf(-(cacc[rt][0][2] + c2)));
            }
        }
    }
}

extern "C" void kernel_launch(void* const* d_in, const int* in_sizes, int n_in,
                              void* d_out, int out_size, void* d_ws, size_t ws_size,
                              hipStream_t stream)
{
    const float* x  = (const float*)d_in[0];
    const float* w0 = (const float*)d_in[1];  const float* b0 = (const float*)d_in[2];
    const float* w1 = (const float*)d_in[3];  const float* b1 = (const float*)d_in[4];
    const float* w2 = (const float*)d_in[5];  const float* b2 = (const float*)d_in[6];
    const float* w3 = (const float*)d_in[7];  const float* b3 = (const float*)d_in[8];
    const float* w4 = (const float*)d_in[9];  const float* b4 = (const float*)d_in[10];
    const float* w5 = (const float*)d_in[11]; const float* b5 = (const float*)d_in[12];
    const float* w6 = (const float*)d_in[13]; const float* b6 = (const float*)d_in[14];
    const float* w7 = (const float*)d_in[15]; const float* b7 = (const float*)d_in[16];
    const float* wf = (const float*)d_in[17]; const float* bf = (const float*)d_in[18];
    const float* wsg= (const float*)d_in[19]; const float* bsg= (const float*)d_in[20];
    const float* wr1= (const float*)d_in[21]; const float* br1= (const float*)d_in[22];
    const float* wr2= (const float*)d_in[23]; const float* br2= (const float*)d_in[24];
    float* out = (float*)d_out;
    const int N = in_sizes[0] / 6;

    prep_weights<<<(N_FRAGS*64 + 255)/256, 256, 0, stream>>>(
        w0,w1,w2,w3,w4,w5,w6,w7,wf,wsg,wr1,wr2);
    nerf_fused<<<N/64, 256, 0, stream>>>(
        x, b0,b1,b2,b3,b4,b5,b6,b7, bf,bsg, br1,br2, out);
}

// Round 8
// 380.814 us; speedup vs baseline: 1.2093x; 1.2093x over previous
//
#include <hip/hip_runtime.h>
#include <hip/hip_fp16.h>
#include <stdint.h>

typedef unsigned int   uint32;
typedef unsigned short ushort_t;
typedef _Float16 half8   __attribute__((ext_vector_type(8)));
typedef float    floatx4 __attribute__((ext_vector_type(4)));

#define DEVINL __device__ __forceinline__

#define N_FRAGS 1172            // total 1KB weight fragments (16x16x32 layout)

// ---------------------------------------------------------------------------
// Fragment-major LDS layout for all MFMA B-operands (r4, verified clean).
//   off(row,f) = (f>>5)*2048 + (row>>4)*512 + ((f>>3)&3)*128 + (row&15)*8 + (f&7)
// B-read for tile (rt,kt): lane L reads 16B at kt*4096B + rt*1024B + L*16B --
// the measured conflict-free stride-1 b128 pattern.
// ---------------------------------------------------------------------------
DEVINL int fragoff(int row, int f) {
    return (f >> 5)*2048 + (row >> 4)*512 + ((f >> 3) & 3)*128 + (row & 15)*8 + (f & 7);
}

// Packed f16 weight fragments in module-owned device memory. Rewritten every
// launch from restored fp32 inputs -> graph-capture safe. L2-resident.
__device__ __align__(16) ushort_t g_ws[(size_t)N_FRAGS * 512];

DEVINL ushort_t f2h_u(float v) { return __half_as_ushort(__float2half(v)); }

// ---------------------------------------------------------------------------
// prep_weights, round-8 rewrite. Old shape: 296 blocks (1.16/CU, ~1 wave/SIMD
// -> no TLP), 16 serial loads/thread -> latency-bound, est. ~90us = the gap
// between metric (383us) and nerf_fused (285us). New shape: one thread per
// (frag, lane, dword): grid = N_FRAGS blocks x 256 thr (~4.6 blocks/CU),
// 2 loads + 1 dword store per thread. frag is block-uniform -> the layer
// search and switch are scalar; wave stores are 256B contiguous.
//
// 16x16x32 A-fragment: lane l (q=l>>4, cc=l&15) holds
// W[k = kt*32 + q*8 + j][n = nt*16 + cc], j=0..7, packed as 4 dwords.
// skip63 (layer-4 concat): k<63 -> row k, k==63 -> 0, k>63 -> row k-1.
// ---------------------------------------------------------------------------
__global__ __launch_bounds__(256) void prep_weights(
    const float* __restrict__ w0, const float* __restrict__ w1,
    const float* __restrict__ w2, const float* __restrict__ w3,
    const float* __restrict__ w4, const float* __restrict__ w5,
    const float* __restrict__ w6, const float* __restrict__ w7,
    const float* __restrict__ wf, const float* __restrict__ wsig,
    const float* __restrict__ wr1, const float* __restrict__ wr2)
{
    const int frag = blockIdx.x;            // 0..N_FRAGS-1, block-uniform
    const int w    = threadIdx.x;           // 0..255
    const int l    = w >> 2;                // fragment lane 0..63
    const int jj   = w & 3;                 // dword index 0..3
    const int q = l >> 4, cc = l & 15;

    constexpr int foff[13] = {0,32,160,288,416,576,704,832,960,1088,1096,1168,1172};
    int t = 0;
    #pragma unroll
    for (int i = 1; i <= 11; ++i) if (frag >= foff[i]) t = i;   // uniform

    const float* W; int fo, ntc, Kr, Nr;
    switch (t) {                            // block-uniform branch
        case 0:  W = w0;   fo = 0;    ntc = 16; Kr = 63;  Nr = 256; break;
        case 1:  W = w1;   fo = 32;   ntc = 16; Kr = 256; Nr = 256; break;
        case 2:  W = w2;   fo = 160;  ntc = 16; Kr = 256; Nr = 256; break;
        case 3:  W = w3;   fo = 288;  ntc = 16; Kr = 256; Nr = 256; break;
        case 4:  W = w4;   fo = 416;  ntc = 16; Kr = 319; Nr = 256; break;
        case 5:  W = w5;   fo = 576;  ntc = 16; Kr = 256; Nr = 256; break;
        case 6:  W = w6;   fo = 704;  ntc = 16; Kr = 256; Nr = 256; break;
        case 7:  W = w7;   fo = 832;  ntc = 16; Kr = 256; Nr = 256; break;
        case 8:  W = wf;   fo = 960;  ntc = 16; Kr = 256; Nr = 256; break;
        case 9:  W = wsig; fo = 1088; ntc = 1;  Kr = 256; Nr = 1;   break;
        case 10: W = wr1;  fo = 1096; ntc = 8;  Kr = 283; Nr = 128; break;
        default: W = wr2;  fo = 1168; ntc = 1;  Kr = 128; Nr = 3;   break;
    }
    const int skip63 = (t == 4);
    const int fl = frag - fo;
    const int nt = fl % ntc;
    const int kt = fl / ntc;
    const int n  = nt*16 + cc;

    ushort_t h2[2];
    #pragma unroll
    for (int e = 0; e < 2; ++e) {
        const int k = kt*32 + q*8 + jj*2 + e;
        float v = 0.f;
        if (n < Nr) {
            if (skip63) {
                if (k != 63) { const int rr = (k < 63) ? k : (k - 1); v = W[(size_t)rr*Nr + n]; }
            } else if (k < Kr) {
                v = W[(size_t)k*Nr + n];
            }
        }
        h2[e] = f2h_u(v);
    }
    const uint32 pk = (uint32)h2[0] | ((uint32)h2[1] << 16);
    ((uint32*)(g_ws + (size_t)frag*512))[l*4 + jj] = pk;   // 256B/wave contig
}

// ---------------------------------------------------------------------------
// Layer: D[n][m] = sum_k W[k][n] * h[m][k]. A-frags direct from L2-hot g_ws,
// B-frags from fragment-major LDS (conflict-free stride-1 b128); both depth-1
// pipelined. First kt uses binit (bias) as the MFMA C-operand. s_setprio(1)
// around each kt's 16-MFMA cluster (T5): with 3 independently-phased blocks
// per CU, compute-phase waves win issue arbitration over staging-phase waves.
// ---------------------------------------------------------------------------
template <int NT_W, int KT, int KT_SPLIT, int NTT>
DEVINL void run_layer(const ushort_t* __restrict__ wsrc,
                      const ushort_t* __restrict__ in0,
                      const ushort_t* __restrict__ in1,
                      int lane, int nt_lo,
                      const floatx4 (&binit)[NT_W], floatx4 (&acc)[4][NT_W])
{
    half8 bfr[2][4];
    half8 afr[2][NT_W];

    auto loadk = [&](int kt, int buf) {
        const ushort_t* bb = ((kt < KT_SPLIT) ? in0 + kt*2048
                                              : in1 + (kt - KT_SPLIT)*2048) + lane*8;
        #pragma unroll
        for (int rt = 0; rt < 4; ++rt)
            bfr[buf][rt] = *(const half8*)(bb + rt*512);
        const ushort_t* wb = wsrc + (size_t)(kt*NTT + nt_lo)*512 + lane*8;
        #pragma unroll
        for (int nt = 0; nt < NT_W; ++nt)
            afr[buf][nt] = *(const half8*)(wb + nt*512);
    };

    loadk(0, 0);
    #pragma unroll
    for (int kt = 0; kt < KT; ++kt) {
        const int cur = kt & 1;
        if (kt + 1 < KT) loadk(kt + 1, cur ^ 1);
        __builtin_amdgcn_s_setprio(1);
        #pragma unroll
        for (int nt = 0; nt < NT_W; ++nt)
            #pragma unroll
            for (int rt = 0; rt < 4; ++rt)
                acc[rt][nt] = __builtin_amdgcn_mfma_f32_16x16x32_f16(
                    afr[cur][nt], bfr[cur][rt],
                    (kt == 0) ? binit[nt] : acc[rt][nt], 0, 0, 0);
        __builtin_amdgcn_s_setprio(0);
    }
}

// epilogue: optional relu, pack to f16 (cvt_pkrtz), 8B LDS store per (rt,nt)
// into the fragment-major layout. Lane (q,cc) holds D[n=ng*16+q*4+r][m=rt*16+cc];
// dest lane' = ((2ng+(q>>1))&3)*16+cc, halfs j=(q&1)*4..+3 of kt-block ng>>1.
template <int NT_W, bool RELU>
DEVINL void epilogue_h(floatx4 (&acc)[4][NT_W], int nt_lo,
                       ushort_t* __restrict__ dsth, int q, int cc)
{
    #pragma unroll
    for (int rt = 0; rt < 4; ++rt) {
        #pragma unroll
        for (int nt = 0; nt < NT_W; ++nt) {
            const int ng = nt_lo + nt;
            floatx4 v = acc[rt][nt];
            if (RELU) {
                v.x = fmaxf(v.x, 0.f); v.y = fmaxf(v.y, 0.f);
                v.z = fmaxf(v.z, 0.f); v.w = fmaxf(v.w, 0.f);
            }
            uint2 u;
            u.x = __builtin_bit_cast(uint32, __builtin_amdgcn_cvt_pkrtz(v.x, v.y));
            u.y = __builtin_bit_cast(uint32, __builtin_amdgcn_cvt_pkrtz(v.z, v.w));
            const int dst = (ng >> 1)*2048 + rt*512
                          + (((2*ng + (q >> 1)) & 3)*16 + cc)*8 + (q & 1)*4;
            *(uint2*)(dsth + dst) = u;
        }
    }
}

// (256,3): the r4 clean regime -- 84 arch VGPR + 64 acc, no spill, 3 blocks/CU.
__global__ __launch_bounds__(256, 3) void nerf_fused(
    const float* __restrict__ x,
    const float* __restrict__ b0, const float* __restrict__ b1,
    const float* __restrict__ b2, const float* __restrict__ b3,
    const float* __restrict__ b4, const float* __restrict__ b5,
    const float* __restrict__ b6, const float* __restrict__ b7,
    const float* __restrict__ bf, const float* __restrict__ bsig,
    const float* __restrict__ br1, const float* __restrict__ br2,
    float* __restrict__ out)
{
    __shared__ __align__(16) ushort_t shh[8*2048];   // h acts, frag-major, 32KB
    __shared__ __align__(16) ushort_t shx[2*2048];   // xyz posenc (64 f), 8KB
    __shared__ __align__(16) ushort_t shd[2048];     // dir posenc (32 f), 4KB

    const int tid  = threadIdx.x;
    const int wave = tid >> 6, lane = tid & 63;
    const int q = lane >> 4, cc = lane & 15;
    const int r0 = blockIdx.x * 64;
    const ushort_t* ws = g_ws;

    // ---- positional encoding (row = lane, job-set = wave) ----
    {
        const int r = lane;
        const float* xr = x + (size_t)(r0 + r)*6;
        for (int j = wave; j < 42; j += 4) {
            if (j < 30) {               // xyz: F=10, layout 3 + f*6 + s*3 + a
                int f = j/3, a = j%3;
                float v = xr[a] * (float)(1 << f);
                shx[fragoff(r, 3 + f*6 + a)]     = f2h_u(sinf(v));
                shx[fragoff(r, 3 + f*6 + 3 + a)] = f2h_u(cosf(v));
            } else {                    // dir: F=4
                int jj = j - 30, f = jj/3, a = jj%3;
                float v = xr[3+a] * (float)(1 << f);
                shd[fragoff(r, 3 + f*6 + a)]     = f2h_u(sinf(v));
                shd[fragoff(r, 3 + f*6 + 3 + a)] = f2h_u(cosf(v));
            }
        }
        if (wave == 0) {
            #pragma unroll
            for (int a = 0; a < 3; ++a) {
                shx[fragoff(r, a)] = f2h_u(xr[a]);
                shd[fragoff(r, a)] = f2h_u(xr[3+a]);
            }
            shx[fragoff(r, 63)] = 0;                    // k-pad must be 0
            #pragma unroll
            for (int kq = 27; kq < 32; ++kq) shd[fragoff(r, kq)] = 0;
        }
    }
    __syncthreads();

    const float* BS[8] = {b0,b1,b2,b3,b4,b5,b6,b7};
    const int WO[8] = {0,16384,81920,147456,212992,294912,360448,425984};
    const int nt_lo4 = wave * 4;
    const floatx4 vz = {0.f, 0.f, 0.f, 0.f};

    floatx4 acc[4][4];
    floatx4 bl[4];

    // layer 0: 64(xyz) -> 256
    #pragma unroll
    for (int nt = 0; nt < 4; ++nt)
        bl[nt] = *(const floatx4*)(b0 + (nt_lo4 + nt)*16 + q*4);
    run_layer<4,2,2,16>(ws + WO[0], shx, shx, lane, nt_lo4, bl, acc);
    epilogue_h<4,true>(acc, nt_lo4, shh, q, cc);
    __syncthreads();

    // layers 1..7 (layer 4 = skip-concat: 2 kt from xyz, 8 kt from h)
    #pragma unroll
    for (int l = 1; l < 8; ++l) {
        #pragma unroll
        for (int nt = 0; nt < 4; ++nt)
            bl[nt] = *(const floatx4*)(BS[l] + (nt_lo4 + nt)*16 + q*4);
        if (l == 4)
            run_layer<4,10,2,16>(ws + WO[4], shx, shh, lane, nt_lo4, bl, acc);
        else
            run_layer<4,8,8,16>(ws + WO[l], shh, shh, lane, nt_lo4, bl, acc);
        __syncthreads();   // all waves done reading shh before epilogue overwrites
        epilogue_h<4,true>(acc, nt_lo4, shh, q, cc);
        __syncthreads();   // epilogue visible before next layer reads
    }

    // sigma head: wave 0 only (barrier-free region, overlaps others' final)
    if (wave == 0) {
        floatx4 sacc[4][1];
        const floatx4 bz[1] = {vz};
        run_layer<1,8,8,1>(ws + 557056, shh, shh, lane, 0, bz, sacc);
        if (q == 0) {                  // feature 0 lives in reg 0 of quad 0
            const float bs_ = bsig[0];
            #pragma unroll
            for (int rt = 0; rt < 4; ++rt)
                out[(size_t)(r0 + rt*16 + cc)*4 + 3] = sacc[rt][0].x + bs_;
        }
    }

    // final: 256 -> 256, NO relu (barrier also covers in-flight sigma reads)
    #pragma unroll
    for (int nt = 0; nt < 4; ++nt)
        bl[nt] = *(const floatx4*)(bf + (nt_lo4 + nt)*16 + q*4);
    run_layer<4,8,8,16>(ws + 491520, shh, shh, lane, nt_lo4, bl, acc);
    __syncthreads();
    epilogue_h<4,false>(acc, nt_lo4, shh, q, cc);
    __syncthreads();

    // rgb1: [final(256) | dir(27->32)] -> 128, relu
    {
        floatx4 racc[4][2];
        floatx4 bl2[2];
        #pragma unroll
        for (int nt = 0; nt < 2; ++nt)
            bl2[nt] = *(const floatx4*)(br1 + (wave*2 + nt)*16 + q*4);
        run_layer<2,9,8,8>(ws + 561152, shh, shd, lane, wave*2, bl2, racc);
        __syncthreads();
        epilogue_h<2,true>(racc, wave*2, shh, q, cc);
        __syncthreads();
    }

    // rgb2: 128 -> 3, sigmoid, store rgb (wave 0 only)
    if (wave == 0) {
        floatx4 cacc[4][1];
        const floatx4 bz[1] = {vz};
        run_layer<1,4,4,1>(ws + 598016, shh, shh, lane, 0, bz, cacc);
        if (q == 0) {
            const float c0 = br2[0], c1 = br2[1], c2 = br2[2];
            #pragma unroll
            for (int rt = 0; rt < 4; ++rt) {
                const size_t o = (size_t)(r0 + rt*16 + cc)*4;
                out[o+0] = 1.f/(1.f + expf(-(cacc[rt][0].x + c0)));
                out[o+1] = 1.f/(1.f + expf(-(cacc[rt][0].y + c1)));
                out[o+2] = 1.f/(1.f + expf(-(cacc[rt][0].z + c2)));
            }
        }
    }
}

extern "C" void kernel_launch(void* const* d_in, const int* in_sizes, int n_in,
                              void* d_out, int out_size, void* d_ws, size_t ws_size,
                              hipStream_t stream)
{
    const float* x  = (const float*)d_in[0];
    const float* w0 = (const float*)d_in[1];  const float* b0 = (const float*)d_in[2];
    const float* w1 = (const float*)d_in[3];  const float* b1 = (const float*)d_in[4];
    const float* w2 = (const float*)d_in[5];  const float* b2 = (const float*)d_in[6];
    const float* w3 = (const float*)d_in[7];  const float* b3 = (const float*)d_in[8];
    const float* w4 = (const float*)d_in[9];  const float* b4 = (const float*)d_in[10];
    const float* w5 = (const float*)d_in[11]; const float* b5 = (const float*)d_in[12];
    const float* w6 = (const float*)d_in[13]; const float* b6 = (const float*)d_in[14];
    const float* w7 = (const float*)d_in[15]; const float* b7 = (const float*)d_in[16];
    const float* wf = (const float*)d_in[17]; const float* bf = (const float*)d_in[18];
    const float* wsg= (const float*)d_in[19]; const float* bsg= (const float*)d_in[20];
    const float* wr1= (const float*)d_in[21]; const float* br1= (const float*)d_in[22];
    const float* wr2= (const float*)d_in[23]; const float* br2= (const float*)d_in[24];
    float* out = (float*)d_out;
    const int N = in_sizes[0] / 6;

    prep_weights<<<N_FRAGS, 256, 0, stream>>>(
        w0,w1,w2,w3,w4,w5,w6,w7,wf,wsg,wr1,wr2);
    nerf_fused<<<N/64, 256, 0, stream>>>(
        x, b0,b1,b2,b3,b4,b5,b6,b7, bf,bsg, br1,br2, out);
}